// Round 9
// baseline (43.770 us; speedup 1.0000x reference)
//
#include <hip/hip_runtime.h>
#include <hip/hip_bf16.h>
#include <stdint.h>

// B=4, C=256, H=W=64 -> L=4096, POS=16384; n_mem=64, sqrt_fin=16, scale=1/4.
using bf16 = __hip_bfloat16;
typedef __attribute__((ext_vector_type(8))) short bf16x8;
typedef __attribute__((ext_vector_type(4))) float f32x4;

#define CDIM 256
#define LDIM 4096

// LDS map (48 KiB), 32 pos/block, 512 blocks, 2 blocks/CU:
// Xs    @0     : [32 p][256 k] bf16, 16B-unit XOR swizzle (16 KB)  -- dead after a_cache load
// QSW   @0     : overlay, [32 p][16 s][8 w] bf16 (8 KB)
// pooled@8192  : overlay, [32 p][64 n] bf16, unit XOR swizzle (4 KB)
// rings @16384 : 8 waves x 4KB (4 slots x 1KB = [16 cols][32 k]) (32 KB)
//                reused at end as Mlds [256 o2][64 n] (32 KB)
#define POOL_OFF 8192
#define RINGS_OFF 16384

__device__ __forceinline__ void gload16(void* lds, const void* g) {
  auto* l3 = (__attribute__((address_space(3))) char*)(uintptr_t)lds;
  auto* g1 = (const __attribute__((address_space(1))) char*)(uintptr_t)g;
  __builtin_amdgcn_global_load_lds((const __attribute__((address_space(1))) void*)g1,
                                   (__attribute__((address_space(3))) void*)l3, 16, 0, 0);
}

template <int CTRL>
__device__ __forceinline__ float dpp_add(float v) {
  int p = __builtin_amdgcn_update_dpp(0, __float_as_int(v), CTRL, 0xf, 0xf, true);
  return v + __int_as_float(p);
}

__device__ __forceinline__ float b2f(short h) {
  return __uint_as_float(((uint32_t)(uint16_t)h) << 16);
}

// ---------- prep: weight casts + MmB[o][n] = bf16(sum_c v[n][c]*Wo[o][c]) ----------
__global__ void prep_kernel(const float* __restrict__ Wq, const float* __restrict__ Wk,
                            const float* __restrict__ v, const float* __restrict__ Wo,
                            bf16* __restrict__ Wqb, bf16* __restrict__ Wkb,
                            bf16* __restrict__ MmBg) {
  int bid = blockIdx.x, t = threadIdx.x;
  if (bid < 512) {
    const float* src = (bid < 256) ? Wq : Wk;
    bf16* dst = (bid < 256) ? Wqb : Wkb;
    int base = (bid & 255) * 1024 + t * 4;
    float4 f = *(const float4*)(src + base);
    dst[base + 0] = __float2bfloat16(f.x);
    dst[base + 1] = __float2bfloat16(f.y);
    dst[base + 2] = __float2bfloat16(f.z);
    dst[base + 3] = __float2bfloat16(f.w);
  } else {
    __shared__ float red[256];
    int o = bid - 512;
    int n = t >> 2, cg = t & 3;
    const float* vr = v + n * CDIM + cg * 64;
    const float* wr = Wo + o * CDIM + cg * 64;
    float a = 0.f;
    for (int c = 0; c < 64; c++) a += vr[c] * wr[c];
    red[t] = a;
    __syncthreads();
    if (t < 64)
      MmBg[o * 64 + t] =
          __float2bfloat16(red[t * 4] + red[t * 4 + 1] + red[t * 4 + 2] + red[t * 4 + 3]);
  }
}

// stage granule c (runtime uniform, 0..127; <64 = Q, >=64 = K) into compile-time SLOT
// granule = 16 cols x 32 k = 1 KB = ONE gload16. Per-lane source pre-swizzled (srcoff).
#define STAGE_G(c, SLOT)                                                                   \
  {                                                                                        \
    const char* wsrc_ = ((c) < 64) ? (const char*)Wqb : (const char*)Wkb;                  \
    int lc_ = (c) & 63;                                                                    \
    gload16((void*)(ringw + (SLOT) * 1024),                                                \
            wsrc_ + (size_t)((w * 128 + (lc_ >> 3) * 16) * 512 + (lc_ & 7) * 64) + srcoff);\
  }

#define VMWAIT(N) asm volatile("s_waitcnt vmcnt(" #N ")" ::: "memory")

// one granule: lgkm fence (ring-reuse safety) -> stage +3 -> counted wait -> 1 ds_read + 2 MFMA
#define GRAN(GB, KQ, WN)                                                                   \
  {                                                                                        \
    asm volatile("s_waitcnt lgkmcnt(0)" ::: "memory");                                     \
    __builtin_amdgcn_sched_barrier(0);                                                     \
    int tg_ = (GB) + ot * 8 + (KQ) + 3;                                                    \
    if (tg_ < 128) { STAGE_G(tg_, ((KQ) + 3) & 3); }                                       \
    VMWAIT(WN);                                                                            \
    __builtin_amdgcn_sched_barrier(0);                                                     \
    bf16x8 bf_ = *(const bf16x8*)(ringw + ((KQ) & 3) * 1024 + s * 64 +                     \
                                  ((g ^ ((s >> 1) & 3)) << 4));                            \
    acc[0] = __builtin_amdgcn_mfma_f32_16x16x32_bf16(a_cache[0][KQ], bf_, acc[0], 0, 0, 0);\
    acc[1] = __builtin_amdgcn_mfma_f32_16x16x32_bf16(a_cache[1][KQ], bf_, acc[1], 0, 0, 0);\
  }

// K-tile epilogue: DPP s-reduce over 16 lanes + swizzled pooled write (8 values, lanes s<8)
#define K_EPI                                                                              \
  {                                                                                        \
    float bkv = bk[w * 128 + ot * 16 + s];                                                 \
    float red[8];                                                                          \
    _Pragma("unroll") for (int mf = 0; mf < 2; mf++)                                       \
        _Pragma("unroll") for (int r = 0; r < 4; r++) {                                    \
      float tt = qreg[mf][r] * fmaxf(acc[mf][r] + bkv, 0.f);                               \
      tt = dpp_add<0x128>(tt);                                                             \
      tt = dpp_add<0x124>(tt);                                                             \
      tt = dpp_add<0x122>(tt);                                                             \
      tt = dpp_add<0x121>(tt);                                                             \
      red[mf * 4 + r] = tt;                                                                \
    }                                                                                      \
    float a0 = (s & 1) ? red[1] : red[0];                                                  \
    float a1 = (s & 1) ? red[3] : red[2];                                                  \
    float a2 = (s & 1) ? red[5] : red[4];                                                  \
    float a3 = (s & 1) ? red[7] : red[6];                                                  \
    float b0 = (s & 2) ? a1 : a0;                                                          \
    float b1 = (s & 2) ? a3 : a2;                                                          \
    float val = (s & 4) ? b1 : b0;                                                         \
    int pos_l = ((s >> 2) & 1) * 16 + g * 4 + (s & 3);                                     \
    int n = w * 8 + ot;                                                                    \
    if (s < 8)                                                                             \
      *(bf16*)(smem + POOL_OFF + pos_l * 128 + ((n ^ ((pos_l & 7) << 3)) * 2)) =           \
          __float2bfloat16(val);                                                           \
  }

__global__ __launch_bounds__(512, 4) void fused_kernel(
    const float* __restrict__ x, const bf16* __restrict__ Wqb, const bf16* __restrict__ Wkb,
    const float* __restrict__ bq, const float* __restrict__ bk,
    const bf16* __restrict__ MmBg, const float* __restrict__ bo, float* __restrict__ out) {
  __shared__ __align__(16) char smem[49152];
  const int tid = threadIdx.x;
  const int w = tid >> 6, lane = tid & 63;
  const int s = lane & 15, g = lane >> 4;
  const int pos0 = blockIdx.x * 32;
  const int bb = pos0 >> 12, l0 = pos0 & (LDIM - 1);
  char* ringw = smem + RINGS_OFF + w * 4096;
  // per-lane source offset within a granule: row = lane>>2, unit u_log = (lane&3)^((lane>>3)&3)
  const int srcoff = (lane >> 2) * 512 + (((lane & 3) ^ ((lane >> 3) & 3)) << 4);

  // ---- prologue: prefetch granules 0,1,2 (Q, ot0, kq0..2) into slots 0,1,2 ----
  STAGE_G(0, 0);
  __builtin_amdgcn_sched_barrier(0);
  STAGE_G(1, 1);
  __builtin_amdgcn_sched_barrier(0);
  STAGE_G(2, 2);
  __builtin_amdgcn_sched_barrier(0);

  // ---- X stage: x [C][L] f32 -> Xs [32 p][256 k] bf16, swizzled scatter ----
  // 2048 float4 slots = 256 k x 8 (p/4); 512 threads x 4 iterations
#pragma unroll
  for (int j = 0; j < 4; j++) {
    int slot = j * 512 + tid;
    int k = slot >> 3, p0 = (slot & 7) * 4;
    float4 f = *(const float4*)(x + ((size_t)bb * CDIM + k) * LDIM + l0 + p0);
    float fv[4] = {f.x, f.y, f.z, f.w};
#pragma unroll
    for (int jj = 0; jj < 4; jj++) {
      int p = p0 + jj;
      *(bf16*)(smem + p * 512 + (((k >> 3) ^ (p & 7)) << 4) + (k & 7) * 2) =
          __float2bfloat16(fv[jj]);
    }
  }
  asm volatile("s_waitcnt lgkmcnt(0)" ::: "memory");
  __builtin_amdgcn_s_barrier();
  __builtin_amdgcn_sched_barrier(0);

  // ---- A fragments -> registers: 16 x bf16x8 (held through Q and K loops) ----
  bf16x8 a_cache[2][8];
#pragma unroll
  for (int mf = 0; mf < 2; mf++) {
    int arow = mf * 16 + s;
#pragma unroll
    for (int kt = 0; kt < 8; kt++)
      a_cache[mf][kt] =
          *(const bf16x8*)(smem + arow * 512 + (((kt * 4 + g) ^ (arow & 7)) << 4));
  }

  // ================= Q projection: 8 o-tiles x 8 k-granules, free-run =================
  float qacc[2][4] = {};
#pragma unroll 1
  for (int ot = 0; ot < 8; ot++) {
    f32x4 acc[2] = {};
    GRAN(0, 0, 3) GRAN(0, 1, 3) GRAN(0, 2, 3) GRAN(0, 3, 3)
    GRAN(0, 4, 3) GRAN(0, 5, 3) GRAN(0, 6, 3) GRAN(0, 7, 3)
    float bqv = bq[w * 128 + ot * 16 + s];
#pragma unroll
    for (int mf = 0; mf < 2; mf++)
#pragma unroll
      for (int r = 0; r < 4; r++) qacc[mf][r] += fmaxf(acc[mf][r] + bqv, 0.f);
  }

  // ---- merge qsum across 8 waves via bf16 LDS (QSW overlays dead Xs) ----
#pragma unroll
  for (int mf = 0; mf < 2; mf++)
#pragma unroll
    for (int r = 0; r < 4; r++) {
      int pos_l = mf * 16 + g * 4 + r;
      *(bf16*)(smem + ((pos_l * 16 + s) * 8 + w) * 2) = __float2bfloat16(qacc[mf][r]);
    }
  asm volatile("s_waitcnt lgkmcnt(0)" ::: "memory");
  __builtin_amdgcn_s_barrier();
  __builtin_amdgcn_sched_barrier(0);
  float qreg[2][4];
#pragma unroll
  for (int mf = 0; mf < 2; mf++)
#pragma unroll
    for (int r = 0; r < 4; r++) {
      int pos_l = mf * 16 + g * 4 + r;
      bf16x8 vv = *(const bf16x8*)(smem + (pos_l * 16 + s) * 16);
      float sum = 0.f;
#pragma unroll
      for (int j = 0; j < 8; j++) sum += b2f(vv[j]);
      qreg[mf][r] = 0.00390625f * sum;  // (1/4)/64
    }

  // ================= K projection: ot 0..6 free-run, ot=7 peeled with tail waits =================
#pragma unroll 1
  for (int ot = 0; ot < 7; ot++) {
    f32x4 acc[2] = {};
    GRAN(64, 0, 3) GRAN(64, 1, 3) GRAN(64, 2, 3) GRAN(64, 3, 3)
    GRAN(64, 4, 3) GRAN(64, 5, 3) GRAN(64, 6, 3) GRAN(64, 7, 3)
    K_EPI
  }
  {
    const int ot = 7;
    f32x4 acc[2] = {};
    GRAN(64, 0, 3) GRAN(64, 1, 3) GRAN(64, 2, 3) GRAN(64, 3, 3)
    GRAN(64, 4, 3) GRAN(64, 5, 2) GRAN(64, 6, 1) GRAN(64, 7, 0)
    K_EPI
  }

  // ---- join: rings dead (vmcnt 0), pooled written -> stage MmB into rings region ----
  asm volatile("s_waitcnt lgkmcnt(0)" ::: "memory");
  __builtin_amdgcn_s_barrier();
  __builtin_amdgcn_sched_barrier(0);
#pragma unroll
  for (int it = 0; it < 4; it++) {
    int P = it * 512 + w * 64 + lane;
    int row = P >> 3, u = P & 7;
    gload16((void*)(smem + RINGS_OFF + (it * 512 + w * 64) * 16),
            (const char*)MmBg + row * 128 + ((u ^ (row & 7)) << 4));
  }
  asm volatile("s_waitcnt vmcnt(0) lgkmcnt(0)" ::: "memory");
  __builtin_amdgcn_s_barrier();
  __builtin_amdgcn_sched_barrier(0);

  // ================= out = x + pooled @ MmB + bo =================
  {
    char* Mlds = smem + RINGS_OFF;  // [256 o2][64 n], swizzled
    char* Plds = smem + POOL_OFF;   // [32 pos][64 n], swizzled
    f32x4 oacc[2][2] = {};
#pragma unroll
    for (int kt = 0; kt < 2; kt++) {
      bf16x8 pf[2];
#pragma unroll
      for (int nfp = 0; nfp < 2; nfp++) {
        int prow = nfp * 16 + s;
        pf[nfp] = *(const bf16x8*)(Plds + prow * 128 + (((kt * 4 + g) ^ (prow & 7)) << 4));
      }
#pragma unroll
      for (int mfo = 0; mfo < 2; mfo++) {
        int mrow = w * 32 + mfo * 16 + s;
        bf16x8 mfr = *(const bf16x8*)(Mlds + mrow * 128 + (((kt * 4 + g) ^ (mrow & 7)) << 4));
#pragma unroll
        for (int nfp = 0; nfp < 2; nfp++)
          oacc[mfo][nfp] =
              __builtin_amdgcn_mfma_f32_16x16x32_bf16(mfr, pf[nfp], oacc[mfo][nfp], 0, 0, 0);
      }
    }
#pragma unroll
    for (int mfo = 0; mfo < 2; mfo++)
#pragma unroll
      for (int r = 0; r < 4; r++) {
        int o2 = w * 32 + mfo * 16 + g * 4 + r;
        float bov = bo[o2];
        const float* xr = x + ((size_t)(bb * CDIM + o2) * LDIM) + l0;
        float* orow = out + ((size_t)(bb * CDIM + o2) * LDIM) + l0;
#pragma unroll
        for (int nfp = 0; nfp < 2; nfp++) {
          int p = nfp * 16 + s;
          orow[p] = xr[p] + oacc[mfo][nfp][r] + bov;
        }
      }
  }
}

extern "C" void kernel_launch(void* const* d_in, const int* in_sizes, int n_in,
                              void* d_out, int out_size, void* d_ws, size_t ws_size,
                              hipStream_t stream) {
  (void)in_sizes; (void)n_in; (void)out_size; (void)ws_size;
  const float* x = (const float*)d_in[0];
  const float* Wq = (const float*)d_in[1];
  const float* bq = (const float*)d_in[2];
  const float* Wk = (const float*)d_in[3];
  const float* bk = (const float*)d_in[4];
  const float* v = (const float*)d_in[5];
  const float* Wo = (const float*)d_in[6];
  const float* bo = (const float*)d_in[7];
  float* out = (float*)d_out;

  char* ws = (char*)d_ws;
  bf16* Wqb = (bf16*)ws;                   // 524,288
  bf16* Wkb = (bf16*)(ws + 524288);        // 524,288
  bf16* MmBg = (bf16*)(ws + 1048576);      // 32,768  (end 1,081,344)

  prep_kernel<<<768, 256, 0, stream>>>(Wq, Wk, v, Wo, Wqb, Wkb, MmBg);
  fused_kernel<<<512, 512, 0, stream>>>(x, Wqb, Wkb, bq, bk, MmBg, bo, out);
}

// Round 10
// 36.234 us; speedup vs baseline: 1.2080x; 1.2080x over previous
//
#include <hip/hip_runtime.h>
#include <hip/hip_bf16.h>
#include <stdint.h>

// B=4, C=256, H=W=64 -> L=4096, POS=16384; n_mem=64, sqrt_fin=16, scale=1/4.
using bf16 = __hip_bfloat16;
typedef __attribute__((ext_vector_type(8))) short bf16x8;
typedef __attribute__((ext_vector_type(4))) float f32x4;

#define CDIM 256
#define LDIM 4096

// LDS map (144 KiB), 64 pos/block, 256 blocks:
// Xs    @0      : [64 p][256 k] bf16, 16B-unit XOR swizzle (32 KB)
//                 overlay after Q loop: QSW [64p][16s][8w] bf16 @0 (16 KB),
//                                       pooled [64p][64n] bf16 @16384 (8 KB)
// rings @32768  : 8 waves x 14 KB (7 slots x 2 KB granule [16 outs][64 k]) (112 KB)
//                 reused at join as Mlds [256 o2][64 n] (first 32 KB)
#define POOL_OFF 16384
#define RINGS_OFF 32768
#define RING_STRIDE 14336  // 7 * 2048

__device__ __forceinline__ void gload16(void* lds, const void* g) {
  auto* l3 = (__attribute__((address_space(3))) char*)(uintptr_t)lds;
  auto* g1 = (const __attribute__((address_space(1))) char*)(uintptr_t)g;
  __builtin_amdgcn_global_load_lds((const __attribute__((address_space(1))) void*)g1,
                                   (__attribute__((address_space(3))) void*)l3, 16, 0, 0);
}

template <int CTRL>
__device__ __forceinline__ float dpp_add(float v) {
  int p = __builtin_amdgcn_update_dpp(0, __float_as_int(v), CTRL, 0xf, 0xf, true);
  return v + __int_as_float(p);
}

__device__ __forceinline__ float b2f(short h) {
  return __uint_as_float(((uint32_t)(uint16_t)h) << 16);
}

// ---------- prep: weight casts + MmB[o][n] = bf16(sum_c v[n][c]*Wo[o][c]) ----------
__global__ void prep_kernel(const float* __restrict__ Wq, const float* __restrict__ Wk,
                            const float* __restrict__ v, const float* __restrict__ Wo,
                            bf16* __restrict__ Wqb, bf16* __restrict__ Wkb,
                            bf16* __restrict__ MmBg) {
  int bid = blockIdx.x, t = threadIdx.x;
  if (bid < 512) {
    const float* src = (bid < 256) ? Wq : Wk;
    bf16* dst = (bid < 256) ? Wqb : Wkb;
    int base = (bid & 255) * 1024 + t * 4;
    float4 f = *(const float4*)(src + base);
    dst[base + 0] = __float2bfloat16(f.x);
    dst[base + 1] = __float2bfloat16(f.y);
    dst[base + 2] = __float2bfloat16(f.z);
    dst[base + 3] = __float2bfloat16(f.w);
  } else {
    __shared__ float red[256];
    int o = bid - 512;
    int n = t >> 2, cg = t & 3;
    const float* vr = v + n * CDIM + cg * 64;
    const float* wr = Wo + o * CDIM + cg * 64;
    float a = 0.f;
    for (int c = 0; c < 64; c++) a += vr[c] * wr[c];
    red[t] = a;
    __syncthreads();
    if (t < 64)
      MmBg[o * 64 + t] =
          __float2bfloat16(red[t * 4] + red[t * 4 + 1] + red[t * 4 + 2] + red[t * 4 + 3]);
  }
}

// stage granule TG (0..63 global; chunk TG>>2 selects Q/K + 16-out row group,
// TG&3 selects the 64-k quarter) into ring slot TG%7 of this wave's ring.
template <int TG>
__device__ __forceinline__ void stage(const char* Wqb, const char* Wkb, char* ringw,
                                      int w, int lane) {
  constexpr int CH = TG >> 2;           // 0..15 (0-7 Q, 8-15 K)
  constexpr int SLOT = TG % 7;
  constexpr int KOFF = (TG & 3) * 128;  // byte offset along 512B row
  const char* wsrc = (CH < 8) ? Wqb : Wkb;
  const int rowbase = w * 128 + (CH & 7) * 16;
#pragma unroll
  for (int inst = 0; inst < 2; inst++) {
    int P = inst * 64 + lane;
    int row = P >> 3, u = P & 7;
    gload16((void*)(ringw + SLOT * 2048 + inst * 1024),
            wsrc + (size_t)(rowbase + row) * 512 + KOFF + ((u ^ (row & 7)) << 4));
  }
}

// one granule: lgkm fence (ring-reuse safety) -> stage +6 ahead -> counted vmcnt
// (steady 12 = 6 granules x 2 loads; exact tail ramp) -> 2x{ds_read, 4 MFMA}
template <int G>
__device__ __forceinline__ void gran(const char* Wqb, const char* Wkb, char* ringw,
                                     int w, int lane, int s, int g4,
                                     const bf16x8 (&a_cache)[4][8], f32x4 (&acc)[4]) {
  asm volatile("s_waitcnt lgkmcnt(0)" ::: "memory");
  __builtin_amdgcn_sched_barrier(0);
  if constexpr (G + 6 < 64) stage<G + 6>(Wqb, Wkb, ringw, w, lane);
  constexpr int WN = (G >= 58) ? (63 - G) * 2 : 12;
  asm volatile("s_waitcnt vmcnt(%0)" ::"n"(WN) : "memory");
  __builtin_amdgcn_sched_barrier(0);
  constexpr int SLOT = G % 7;
  constexpr int KQ = G & 3;
#pragma unroll
  for (int kt2 = 0; kt2 < 2; kt2++) {
    bf16x8 bf_ = *(const bf16x8*)(ringw + SLOT * 2048 + s * 128 +
                                  (((kt2 * 4 + g4) ^ (s & 7)) << 4));
#pragma unroll
    for (int mf = 0; mf < 4; mf++)
      acc[mf] =
          __builtin_amdgcn_mfma_f32_16x16x32_bf16(a_cache[mf][KQ * 2 + kt2], bf_, acc[mf], 0, 0, 0);
  }
}

template <int C>
__device__ __forceinline__ void chunkQ(const char* Wqb, const char* Wkb, char* ringw,
                                       int w, int lane, int s, int g4,
                                       const bf16x8 (&a_cache)[4][8],
                                       const float (&bqr)[8], float (&qacc)[4][4]) {
  f32x4 acc[4] = {};
  gran<C * 4 + 0>(Wqb, Wkb, ringw, w, lane, s, g4, a_cache, acc);
  gran<C * 4 + 1>(Wqb, Wkb, ringw, w, lane, s, g4, a_cache, acc);
  gran<C * 4 + 2>(Wqb, Wkb, ringw, w, lane, s, g4, a_cache, acc);
  gran<C * 4 + 3>(Wqb, Wkb, ringw, w, lane, s, g4, a_cache, acc);
  float bqv = bqr[C];
#pragma unroll
  for (int mf = 0; mf < 4; mf++)
#pragma unroll
    for (int r = 0; r < 4; r++) qacc[mf][r] += fmaxf(acc[mf][r] + bqv, 0.f);
}

template <int C>
__device__ __forceinline__ void chunkK(const char* Wqb, const char* Wkb, char* smem,
                                       char* ringw, int w, int lane, int s, int g4,
                                       const bf16x8 (&a_cache)[4][8],
                                       const float (&bkr)[8], const float (&qreg)[4][4]) {
  f32x4 acc[4] = {};
  gran<32 + C * 4 + 0>(Wqb, Wkb, ringw, w, lane, s, g4, a_cache, acc);
  gran<32 + C * 4 + 1>(Wqb, Wkb, ringw, w, lane, s, g4, a_cache, acc);
  gran<32 + C * 4 + 2>(Wqb, Wkb, ringw, w, lane, s, g4, a_cache, acc);
  gran<32 + C * 4 + 3>(Wqb, Wkb, ringw, w, lane, s, g4, a_cache, acc);
  float bkv = bkr[C];
  float red[16];
#pragma unroll
  for (int mf = 0; mf < 4; mf++)
#pragma unroll
    for (int r = 0; r < 4; r++) {
      float tt = qreg[mf][r] * fmaxf(acc[mf][r] + bkv, 0.f);
      tt = dpp_add<0x128>(tt);  // row_ror:8
      tt = dpp_add<0x124>(tt);  // row_ror:4
      tt = dpp_add<0x122>(tt);  // row_ror:2
      tt = dpp_add<0x121>(tt);  // row_ror:1
      red[mf * 4 + r] = tt;     // sum over 16 s-lanes, in all lanes
    }
  float a0 = (s & 1) ? red[1] : red[0];
  float a1 = (s & 1) ? red[3] : red[2];
  float a2 = (s & 1) ? red[5] : red[4];
  float a3 = (s & 1) ? red[7] : red[6];
  float a4 = (s & 1) ? red[9] : red[8];
  float a5 = (s & 1) ? red[11] : red[10];
  float a6 = (s & 1) ? red[13] : red[12];
  float a7 = (s & 1) ? red[15] : red[14];
  float b0 = (s & 2) ? a1 : a0;
  float b1 = (s & 2) ? a3 : a2;
  float b2 = (s & 2) ? a5 : a4;
  float b3 = (s & 2) ? a7 : a6;
  float c0 = (s & 4) ? b1 : b0;
  float c1 = (s & 4) ? b3 : b2;
  float val = (s & 8) ? c1 : c0;
  int pos_l = (s >> 2) * 16 + g4 * 4 + (s & 3);
  int n = w * 8 + C;
  *(bf16*)(smem + POOL_OFF + pos_l * 128 + ((n ^ ((pos_l & 7) << 3)) * 2)) =
      __float2bfloat16(val);
}

__global__ __launch_bounds__(512, 2) void fused_kernel(
    const float* __restrict__ x, const bf16* __restrict__ Wqb_, const bf16* __restrict__ Wkb_,
    const float* __restrict__ bq, const float* __restrict__ bk,
    const bf16* __restrict__ MmBg, const float* __restrict__ bo, float* __restrict__ out) {
  __shared__ __align__(16) char smem[147456];
  const int tid = threadIdx.x;
  const int w = tid >> 6, lane = tid & 63;
  const int s = lane & 15, g4 = lane >> 4;
  const int pos0 = blockIdx.x * 64;
  const int bb = pos0 >> 12, l0 = pos0 & (LDIM - 1);
  char* ringw = smem + RINGS_OFF + w * RING_STRIDE;
  const char* Wqb = (const char*)Wqb_;
  const char* Wkb = (const char*)Wkb_;

  // ---- bias hoist (keeps vmcnt ledger clean: no scalar loads inside the pipeline) ----
  float bqr[8], bkr[8];
#pragma unroll
  for (int ot = 0; ot < 8; ot++) {
    bqr[ot] = bq[w * 128 + ot * 16 + s];
    bkr[ot] = bk[w * 128 + ot * 16 + s];
  }

  // ---- X stage FIRST (its loads retire via in-stage waits; issued before staging so
  //      compiler waits on them never drain the weight-staging queue) ----
#pragma unroll
  for (int j = 0; j < 8; j++) {
    int slot = j * 512 + tid;  // 4096 float4 slots = 256 k x 16 (p/4)
    int k = slot >> 4, p0 = (slot & 15) * 4;
    float4 f = *(const float4*)(x + ((size_t)bb * CDIM + k) * LDIM + l0 + p0);
    float fv[4] = {f.x, f.y, f.z, f.w};
#pragma unroll
    for (int jj = 0; jj < 4; jj++) {
      int p = p0 + jj;
      *(bf16*)(smem + p * 512 + (((k >> 3) ^ (p & 7)) << 4) + (k & 7) * 2) =
          __float2bfloat16(fv[jj]);
    }
  }

  // ---- prologue staging: granules 0..5 (depth-6 pipeline prime) ----
  stage<0>(Wqb, Wkb, ringw, w, lane);
  __builtin_amdgcn_sched_barrier(0);
  stage<1>(Wqb, Wkb, ringw, w, lane);
  __builtin_amdgcn_sched_barrier(0);
  stage<2>(Wqb, Wkb, ringw, w, lane);
  __builtin_amdgcn_sched_barrier(0);
  stage<3>(Wqb, Wkb, ringw, w, lane);
  __builtin_amdgcn_sched_barrier(0);
  stage<4>(Wqb, Wkb, ringw, w, lane);
  __builtin_amdgcn_sched_barrier(0);
  stage<5>(Wqb, Wkb, ringw, w, lane);
  __builtin_amdgcn_sched_barrier(0);

  asm volatile("s_waitcnt lgkmcnt(0)" ::: "memory");
  __builtin_amdgcn_s_barrier();
  __builtin_amdgcn_sched_barrier(0);

  // ---- A fragments -> registers: 32 x bf16x8 (Xs region is overwritten later,
  //      so these MUST live in registers through both loops) ----
  bf16x8 a_cache[4][8];
#pragma unroll
  for (int mf = 0; mf < 4; mf++) {
    int arow = mf * 16 + s;
#pragma unroll
    for (int kt = 0; kt < 8; kt++)
      a_cache[mf][kt] =
          *(const bf16x8*)(smem + arow * 512 + (((kt * 4 + g4) ^ (arow & 7)) << 4));
  }

  // ================= Q projection: chunks 0..7 (granules 0..31) =================
  float qacc[4][4] = {};
  chunkQ<0>(Wqb, Wkb, ringw, w, lane, s, g4, a_cache, bqr, qacc);
  chunkQ<1>(Wqb, Wkb, ringw, w, lane, s, g4, a_cache, bqr, qacc);
  chunkQ<2>(Wqb, Wkb, ringw, w, lane, s, g4, a_cache, bqr, qacc);
  chunkQ<3>(Wqb, Wkb, ringw, w, lane, s, g4, a_cache, bqr, qacc);
  chunkQ<4>(Wqb, Wkb, ringw, w, lane, s, g4, a_cache, bqr, qacc);
  chunkQ<5>(Wqb, Wkb, ringw, w, lane, s, g4, a_cache, bqr, qacc);
  chunkQ<6>(Wqb, Wkb, ringw, w, lane, s, g4, a_cache, bqr, qacc);
  chunkQ<7>(Wqb, Wkb, ringw, w, lane, s, g4, a_cache, bqr, qacc);

  // ---- merge qsum across 8 waves via bf16 LDS (QSW overlays dead Xs @0) ----
#pragma unroll
  for (int mf = 0; mf < 4; mf++)
#pragma unroll
    for (int r = 0; r < 4; r++) {
      int pos_l = mf * 16 + g4 * 4 + r;
      *(bf16*)(smem + ((pos_l * 16 + s) * 8 + w) * 2) = __float2bfloat16(qacc[mf][r]);
    }
  asm volatile("s_waitcnt lgkmcnt(0)" ::: "memory");
  __builtin_amdgcn_s_barrier();
  __builtin_amdgcn_sched_barrier(0);
  float qreg[4][4];
#pragma unroll
  for (int mf = 0; mf < 4; mf++)
#pragma unroll
    for (int r = 0; r < 4; r++) {
      int pos_l = mf * 16 + g4 * 4 + r;
      bf16x8 vv = *(const bf16x8*)(smem + (pos_l * 16 + s) * 16);
      float sum = 0.f;
#pragma unroll
      for (int j = 0; j < 8; j++) sum += b2f(vv[j]);
      qreg[mf][r] = 0.00390625f * sum;  // (1/4)/64
    }

  // ================= K projection: chunks 0..7 (granules 32..63, exact tail) =================
  chunkK<0>(Wqb, Wkb, smem, ringw, w, lane, s, g4, a_cache, bkr, qreg);
  chunkK<1>(Wqb, Wkb, smem, ringw, w, lane, s, g4, a_cache, bkr, qreg);
  chunkK<2>(Wqb, Wkb, smem, ringw, w, lane, s, g4, a_cache, bkr, qreg);
  chunkK<3>(Wqb, Wkb, smem, ringw, w, lane, s, g4, a_cache, bkr, qreg);
  chunkK<4>(Wqb, Wkb, smem, ringw, w, lane, s, g4, a_cache, bkr, qreg);
  chunkK<5>(Wqb, Wkb, smem, ringw, w, lane, s, g4, a_cache, bkr, qreg);
  chunkK<6>(Wqb, Wkb, smem, ringw, w, lane, s, g4, a_cache, bkr, qreg);
  chunkK<7>(Wqb, Wkb, smem, ringw, w, lane, s, g4, a_cache, bkr, qreg);

  // ---- join: rings dead (vmcnt(0) from G=63), pooled written -> stage MmB @32768 ----
  asm volatile("s_waitcnt lgkmcnt(0)" ::: "memory");
  __builtin_amdgcn_s_barrier();
  __builtin_amdgcn_sched_barrier(0);
#pragma unroll
  for (int it = 0; it < 4; it++) {
    int P = it * 512 + tid;
    int row = P >> 3, u = P & 7;
    gload16((void*)(smem + RINGS_OFF + (it * 512 + w * 64) * 16),
            (const char*)MmBg + row * 128 + ((u ^ (row & 7)) << 4));
  }
  asm volatile("s_waitcnt vmcnt(0) lgkmcnt(0)" ::: "memory");
  __builtin_amdgcn_s_barrier();
  __builtin_amdgcn_sched_barrier(0);

  // ================= out = x + pooled @ MmB + bo =================
  {
    char* Mlds = smem + RINGS_OFF;  // [256 o2][64 n], swizzled
    char* Plds = smem + POOL_OFF;   // [64 pos][64 n], swizzled
    f32x4 oacc[2][4] = {};
#pragma unroll
    for (int kt = 0; kt < 2; kt++) {
      bf16x8 pf[4];
#pragma unroll
      for (int nfp = 0; nfp < 4; nfp++) {
        int prow = nfp * 16 + s;
        pf[nfp] = *(const bf16x8*)(Plds + prow * 128 + (((kt * 4 + g4) ^ (prow & 7)) << 4));
      }
#pragma unroll
      for (int mfo = 0; mfo < 2; mfo++) {
        int mrow = w * 32 + mfo * 16 + s;
        bf16x8 mfr = *(const bf16x8*)(Mlds + mrow * 128 + (((kt * 4 + g4) ^ (mrow & 7)) << 4));
#pragma unroll
        for (int nfp = 0; nfp < 4; nfp++)
          oacc[mfo][nfp] =
              __builtin_amdgcn_mfma_f32_16x16x32_bf16(mfr, pf[nfp], oacc[mfo][nfp], 0, 0, 0);
      }
    }
#pragma unroll
    for (int mfo = 0; mfo < 2; mfo++)
#pragma unroll
      for (int r = 0; r < 4; r++) {
        int o2 = w * 32 + mfo * 16 + g4 * 4 + r;
        float bov = bo[o2];
        const float* xr = x + ((size_t)(bb * CDIM + o2) * LDIM) + l0;
        float* orow = out + ((size_t)(bb * CDIM + o2) * LDIM) + l0;
#pragma unroll
        for (int nfp = 0; nfp < 4; nfp++) {
          int p = nfp * 16 + s;
          orow[p] = xr[p] + oacc[mfo][nfp][r] + bov;
        }
      }
  }
}

extern "C" void kernel_launch(void* const* d_in, const int* in_sizes, int n_in,
                              void* d_out, int out_size, void* d_ws, size_t ws_size,
                              hipStream_t stream) {
  (void)in_sizes; (void)n_in; (void)out_size; (void)ws_size;
  const float* x = (const float*)d_in[0];
  const float* Wq = (const float*)d_in[1];
  const float* bq = (const float*)d_in[2];
  const float* Wk = (const float*)d_in[3];
  const float* bk = (const float*)d_in[4];
  const float* v = (const float*)d_in[5];
  const float* Wo = (const float*)d_in[6];
  const float* bo = (const float*)d_in[7];
  float* out = (float*)d_out;

  char* ws = (char*)d_ws;
  bf16* Wqb = (bf16*)ws;                   // 524,288
  bf16* Wkb = (bf16*)(ws + 524288);        // 524,288
  bf16* MmBg = (bf16*)(ws + 1048576);      // 32,768  (end 1,081,344)

  prep_kernel<<<768, 256, 0, stream>>>(Wq, Wk, v, Wo, Wqb, Wkb, MmBg);
  fused_kernel<<<256, 512, 0, stream>>>(x, Wqb, Wkb, bq, bk, MmBg, bo, out);
}